// Round 1
// baseline (383.372 us; speedup 1.0000x reference)
//
#include <hip/hip_runtime.h>
#include <stdint.h>

// ---------------------------------------------------------------------------
// MultiHeadAdaptiveChebyshevLayer: xs = x*scale; T_0..T_7 Chebyshev;
// y[b,h,i,k] = poly[h,i,k] * sum_m T_m * kernel[h,i,m,k]; LayerNorm over
// the 65536-wide flattened (h,i,k) axis.
//
// Strategy:
//   prologue 1: fold poly into kernel, convert to bf16, permute so main
//               kernel's dwordx4 loads are lane-coalesced (16B lane stride).
//   prologue 2: pack gamma/beta as bf16 pairs in a coalesced layout.
//   main:       1 block (1024 thr) per row; thread owns 64 contiguous
//               output features in registers; block-reduce mean/var;
//               normalize from registers; float4 stores.
// Traffic: out write 268 MB (HBM floor ~43us) + ~1.3 GB L2 weight reads
// (under floor after bf16 halving). No second pass over y.
// ---------------------------------------------------------------------------

#define LN_EPS 1e-5f

__device__ __forceinline__ unsigned bf16_rne(float f) {
    unsigned u = __float_as_uint(f);
    unsigned r = u + 0x7fffu + ((u >> 16) & 1u);
    return r >> 16;
}
__device__ __forceinline__ float bf_lo(unsigned u) { return __uint_as_float(u << 16); }
__device__ __forceinline__ float bf_hi(unsigned u) { return __uint_as_float(u & 0xffff0000u); }

// Prologue 1: W2[((w*8 + j)*8 + k)*64 + l] (uint4 = 8 bf16 over m) where the
// main-kernel thread t = w*64 + l owns pair p = t*8 + j.
// Value[m] = kernel[p*64 + m*8 + k] * poly[p*8 + k].
__global__ void fold_weights_kernel(const float* __restrict__ K,
                                    const float* __restrict__ poly,
                                    uint4* __restrict__ W2) {
    int tid = blockIdx.x * blockDim.x + threadIdx.x;   // [0, 65536)
    int p = tid >> 3, k = tid & 7;
    int t = p >> 3, j = p & 7;
    int w = t >> 6, l = t & 63;
    const float* kp = K + (size_t)p * 64 + k;          // stride 8 over m
    float pw = poly[p * 8 + k];
    float v[8];
#pragma unroll
    for (int m = 0; m < 8; ++m) v[m] = kp[m * 8] * pw;
    uint4 q;
    q.x = bf16_rne(v[0]) | (bf16_rne(v[1]) << 16);
    q.y = bf16_rne(v[2]) | (bf16_rne(v[3]) << 16);
    q.z = bf16_rne(v[4]) | (bf16_rne(v[5]) << 16);
    q.w = bf16_rne(v[6]) | (bf16_rne(v[7]) << 16);
    W2[((w * 8 + j) * 8 + k) * 64 + l] = q;
}

// Prologue 2: GB2[c*1024 + t] = uint4 of 4 features f = t*64 + c*4 .. +3,
// each packed (bf16(gamma) | bf16(beta)<<16).
__global__ void pack_gb_kernel(const float* __restrict__ gamma,
                               const float* __restrict__ beta,
                               uint4* __restrict__ GB2) {
    int tid = blockIdx.x * blockDim.x + threadIdx.x;   // [0, 16384)
    int c = tid >> 10, t = tid & 1023;
    int f = t * 64 + c * 4;
    uint4 q;
    q.x = bf16_rne(gamma[f + 0]) | (bf16_rne(beta[f + 0]) << 16);
    q.y = bf16_rne(gamma[f + 1]) | (bf16_rne(beta[f + 1]) << 16);
    q.z = bf16_rne(gamma[f + 2]) | (bf16_rne(beta[f + 2]) << 16);
    q.w = bf16_rne(gamma[f + 3]) | (bf16_rne(beta[f + 3]) << 16);
    GB2[c * 1024 + t] = q;
}

// Main: one block per batch row.
__global__ __launch_bounds__(1024, 4) void cheb_ln_main(
    const float* __restrict__ x, const float* __restrict__ scale,
    const uint4* __restrict__ W2, const uint4* __restrict__ GB2,
    float* __restrict__ out) {
    const int r = blockIdx.x;
    const int t = threadIdx.x;
    const int w = t >> 6, l = t & 63;
    // Thread t owns pairs p = t*8 + j, all in head h = t>>7, i = (t&127)*8 + j.
    const int h = t >> 7;
    const int i0 = (t & 127) * 8;

    const float* xrow = x + (size_t)r * 1024;
    const float4* x4 = (const float4*)(xrow + i0);
    const float4* s4 = (const float4*)(scale + h * 1024 + i0);
    float4 xa = x4[0], xb = x4[1];
    float4 sa = s4[0], sb = s4[1];
    float xs[8] = {xa.x * sa.x, xa.y * sa.y, xa.z * sa.z, xa.w * sa.w,
                   xb.x * sb.x, xb.y * sb.y, xb.z * sb.z, xb.w * sb.w};

    const uint4* wbase = W2 + w * 4096 + l;   // + j*512 + k*64

    float y[64];
    float sum = 0.f, sq = 0.f;
#pragma unroll
    for (int j = 0; j < 8; ++j) {
        float v = xs[j];
        float T[8];
        T[0] = 1.f;
        T[1] = v;
        float t2 = v + v;
#pragma unroll
        for (int m = 2; m < 8; ++m) T[m] = t2 * T[m - 1] - T[m - 2];
#pragma unroll
        for (int k = 0; k < 8; ++k) {
            uint4 q = wbase[j * 512 + k * 64];
            float acc = T[0] * bf_lo(q.x);
            acc = fmaf(T[1], bf_hi(q.x), acc);
            acc = fmaf(T[2], bf_lo(q.y), acc);
            acc = fmaf(T[3], bf_hi(q.y), acc);
            acc = fmaf(T[4], bf_lo(q.z), acc);
            acc = fmaf(T[5], bf_hi(q.z), acc);
            acc = fmaf(T[6], bf_lo(q.w), acc);
            acc = fmaf(T[7], bf_hi(q.w), acc);
            y[j * 8 + k] = acc;
            sum += acc;
            sq = fmaf(acc, acc, sq);
        }
    }

    // Wave reduction (64 lanes), then cross-wave via LDS.
#pragma unroll
    for (int off = 32; off; off >>= 1) {
        sum += __shfl_down(sum, off, 64);
        sq  += __shfl_down(sq,  off, 64);
    }
    __shared__ float red[32];
    if (l == 0) { red[w] = sum; red[w + 16] = sq; }
    __syncthreads();
    float S = 0.f, SQ = 0.f;
#pragma unroll
    for (int q = 0; q < 16; ++q) { S += red[q]; SQ += red[q + 16]; }
    const float inv = 1.f / 65536.f;
    float mu = S * inv;
    float var = fmaf(-mu, mu, SQ * inv);
    float rstd = rsqrtf(var + LN_EPS);

    // Normalize from registers and store (thread owns 64 contiguous outputs).
    float4* o4 = (float4*)(out + (size_t)r * 65536 + t * 64);
    const uint4* gb = GB2 + t;                 // gb[c*1024]
#pragma unroll
    for (int c = 0; c < 16; ++c) {
        uint4 g = gb[c * 1024];
        float4 o;
        o.x = fmaf((y[c * 4 + 0] - mu) * rstd, bf_lo(g.x), bf_hi(g.x));
        o.y = fmaf((y[c * 4 + 1] - mu) * rstd, bf_lo(g.y), bf_hi(g.y));
        o.z = fmaf((y[c * 4 + 2] - mu) * rstd, bf_lo(g.z), bf_hi(g.z));
        o.w = fmaf((y[c * 4 + 3] - mu) * rstd, bf_lo(g.w), bf_hi(g.w));
        o4[c] = o;
    }
}

extern "C" void kernel_launch(void* const* d_in, const int* in_sizes, int n_in,
                              void* d_out, int out_size, void* d_ws, size_t ws_size,
                              hipStream_t stream) {
    const float* x     = (const float*)d_in[0];   // [1024,1024]
    const float* scale = (const float*)d_in[1];   // [8,1024]
    const float* poly  = (const float*)d_in[2];   // [8,1024,8]
    const float* kern  = (const float*)d_in[3];   // [8,1024,8,8]
    const float* gamma = (const float*)d_in[4];   // [65536]
    const float* beta  = (const float*)d_in[5];   // [65536]
    float* out = (float*)d_out;

    uint4* W2  = (uint4*)d_ws;                          // 65536 * 16 B = 1 MiB
    uint4* GB2 = (uint4*)((char*)d_ws + (1u << 20));    // 16384 * 16 B = 256 KiB

    fold_weights_kernel<<<256, 256, 0, stream>>>(kern, poly, W2);
    pack_gb_kernel<<<64, 256, 0, stream>>>(gamma, beta, GB2);
    cheb_ln_main<<<1024, 1024, 0, stream>>>(x, scale, W2, GB2, out);
}

// Round 2
// 318.942 us; speedup vs baseline: 1.2020x; 1.2020x over previous
//
#include <hip/hip_runtime.h>
#include <stdint.h>

// ---------------------------------------------------------------------------
// MultiHeadAdaptiveChebyshevLayer, round 2.
// Ownership change vs R1: thread t owns features f = c*4096 + t*4 + {0..3},
// c = 0..15  ->  every weight load / gamma-beta load / output store is a
// lane-coalesced dwordx4 (16 B lane stride).  y kept as packed bf16 pairs
// (32 VGPRs) to avoid the R1 spills.  xs staged in LDS (32 KB).
//
// For feature f: k = f & 7, pair p = f >> 3 (p = h*1024+i, p in [0,8192)).
// With f = c*4096 + t*4 + d:  p = c*512 + (t>>1),  k = (t&1)*4 + d.
// ---------------------------------------------------------------------------

#define LN_EPS 1e-5f

typedef float vfloat4 __attribute__((ext_vector_type(4)));

__device__ __forceinline__ unsigned bf16_rne(float f) {
    unsigned u = __float_as_uint(f);
    unsigned r = u + 0x7fffu + ((u >> 16) & 1u);
    return r >> 16;
}
__device__ __forceinline__ float bf_lo(unsigned u) { return __uint_as_float(u << 16); }
__device__ __forceinline__ float bf_hi(unsigned u) { return __uint_as_float(u & 0xffff0000u); }

// Prologue 1: fold poly into kernel, bf16-pack over m, permute so that the
// main kernel's load for (c,d) at lane t is W3[(c*4+d)*1024 + t].
__global__ void fold_weights_kernel(const float* __restrict__ K,
                                    const float* __restrict__ poly,
                                    uint4* __restrict__ W3) {
    int tid = blockIdx.x * blockDim.x + threadIdx.x;   // [0, 65536)
    int p = tid >> 3, k = tid & 7;
    const float* kp = K + (size_t)p * 64 + k;          // stride 8 over m
    float pw = poly[p * 8 + k];
    float v[8];
#pragma unroll
    for (int m = 0; m < 8; ++m) v[m] = kp[m * 8] * pw;
    uint4 q;
    q.x = bf16_rne(v[0]) | (bf16_rne(v[1]) << 16);
    q.y = bf16_rne(v[2]) | (bf16_rne(v[3]) << 16);
    q.z = bf16_rne(v[4]) | (bf16_rne(v[5]) << 16);
    q.w = bf16_rne(v[6]) | (bf16_rne(v[7]) << 16);
    int c = p >> 9;
    int t = ((p & 511) << 1) | (k >> 2);
    int d = k & 3;
    W3[(c * 4 + d) * 1024 + t] = q;
}

// Prologue 2: GB3[tid] covers features f = tid*4 .. +3, each word packs
// (bf16(gamma) | bf16(beta)<<16).  Main kernel reads GB3[c*1024 + t].
__global__ void pack_gb_kernel(const float* __restrict__ gamma,
                               const float* __restrict__ beta,
                               uint4* __restrict__ GB3) {
    int tid = blockIdx.x * blockDim.x + threadIdx.x;   // [0, 16384)
    float4 g = ((const float4*)gamma)[tid];
    float4 b = ((const float4*)beta)[tid];
    uint4 q;
    q.x = bf16_rne(g.x) | (bf16_rne(b.x) << 16);
    q.y = bf16_rne(g.y) | (bf16_rne(b.y) << 16);
    q.z = bf16_rne(g.z) | (bf16_rne(b.z) << 16);
    q.w = bf16_rne(g.w) | (bf16_rne(b.w) << 16);
    GB3[tid] = q;
}

// Main: one block (1024 threads) per batch row.
__global__ __launch_bounds__(1024, 4) void cheb_ln_main(
    const float* __restrict__ x, const float* __restrict__ scale,
    const uint4* __restrict__ W3, const uint4* __restrict__ GB3,
    float* __restrict__ out) {
    __shared__ float xs[8192];
    __shared__ float red[32];
    const int r = blockIdx.x;
    const int t = threadIdx.x;
    const int w = t >> 6, l = t & 63;

    // Stage xs[h*1024 + i] = x[i] * scale[h*1024 + i] into LDS (coalesced;
    // x[t] loaded once and reused across the 8 heads).
    float xv = x[(size_t)r * 1024 + t];
#pragma unroll
    for (int h = 0; h < 8; ++h)
        xs[h * 1024 + t] = xv * scale[h * 1024 + t];
    __syncthreads();

    const int phalf = t >> 1;   // p = c*512 + phalf
    unsigned y2[32];            // 64 y values as packed bf16 pairs
    float sum = 0.f, sq = 0.f;

#pragma unroll
    for (int c = 0; c < 16; ++c) {
        float v = xs[c * 512 + phalf];          // 2-way broadcast, no conflicts
        float T0 = 1.f, T1 = v;
        float v2 = v + v;
        float T2 = v2 * T1 - T0;
        float T3 = v2 * T2 - T1;
        float T4 = v2 * T3 - T2;
        float T5 = v2 * T4 - T3;
        float T6 = v2 * T5 - T4;
        float T7 = v2 * T6 - T5;

        uint4 q0 = W3[(c * 4 + 0) * 1024 + t];  // all four: 16 B lane stride
        uint4 q1 = W3[(c * 4 + 1) * 1024 + t];
        uint4 q2 = W3[(c * 4 + 2) * 1024 + t];
        uint4 q3 = W3[(c * 4 + 3) * 1024 + t];

        float a0, a1, a2, a3;
        {
            a0 = T0 * bf_lo(q0.x); a0 = fmaf(T1, bf_hi(q0.x), a0);
            a0 = fmaf(T2, bf_lo(q0.y), a0); a0 = fmaf(T3, bf_hi(q0.y), a0);
            a0 = fmaf(T4, bf_lo(q0.z), a0); a0 = fmaf(T5, bf_hi(q0.z), a0);
            a0 = fmaf(T6, bf_lo(q0.w), a0); a0 = fmaf(T7, bf_hi(q0.w), a0);
            a1 = T0 * bf_lo(q1.x); a1 = fmaf(T1, bf_hi(q1.x), a1);
            a1 = fmaf(T2, bf_lo(q1.y), a1); a1 = fmaf(T3, bf_hi(q1.y), a1);
            a1 = fmaf(T4, bf_lo(q1.z), a1); a1 = fmaf(T5, bf_hi(q1.z), a1);
            a1 = fmaf(T6, bf_lo(q1.w), a1); a1 = fmaf(T7, bf_hi(q1.w), a1);
            a2 = T0 * bf_lo(q2.x); a2 = fmaf(T1, bf_hi(q2.x), a2);
            a2 = fmaf(T2, bf_lo(q2.y), a2); a2 = fmaf(T3, bf_hi(q2.y), a2);
            a2 = fmaf(T4, bf_lo(q2.z), a2); a2 = fmaf(T5, bf_hi(q2.z), a2);
            a2 = fmaf(T6, bf_lo(q2.w), a2); a2 = fmaf(T7, bf_hi(q2.w), a2);
            a3 = T0 * bf_lo(q3.x); a3 = fmaf(T1, bf_hi(q3.x), a3);
            a3 = fmaf(T2, bf_lo(q3.y), a3); a3 = fmaf(T3, bf_hi(q3.y), a3);
            a3 = fmaf(T4, bf_lo(q3.z), a3); a3 = fmaf(T5, bf_hi(q3.z), a3);
            a3 = fmaf(T6, bf_lo(q3.w), a3); a3 = fmaf(T7, bf_hi(q3.w), a3);
        }
        sum += a0 + a1 + a2 + a3;
        sq = fmaf(a0, a0, sq); sq = fmaf(a1, a1, sq);
        sq = fmaf(a2, a2, sq); sq = fmaf(a3, a3, sq);
        y2[c * 2 + 0] = bf16_rne(a0) | (bf16_rne(a1) << 16);
        y2[c * 2 + 1] = bf16_rne(a2) | (bf16_rne(a3) << 16);
    }

    // Wave reduce (64 lanes) then cross-wave via LDS.
#pragma unroll
    for (int off = 32; off; off >>= 1) {
        sum += __shfl_down(sum, off, 64);
        sq  += __shfl_down(sq,  off, 64);
    }
    if (l == 0) { red[w] = sum; red[w + 16] = sq; }
    __syncthreads();
    float S = 0.f, SQ = 0.f;
#pragma unroll
    for (int q = 0; q < 16; ++q) { S += red[q]; SQ += red[q + 16]; }
    const float inv = 1.f / 65536.f;
    float mu = S * inv;
    float var = fmaf(-mu, mu, SQ * inv);
    float rstd = rsqrtf(var + LN_EPS);

    // Epilogue: unpack y, normalize, affine, nontemporal coalesced stores.
    float* orow = out + (size_t)r * 65536;
#pragma unroll
    for (int c = 0; c < 16; ++c) {
        uint4 g = GB3[c * 1024 + t];
        unsigned u0 = y2[c * 2 + 0], u1 = y2[c * 2 + 1];
        vfloat4 o;
        o.x = fmaf((bf_lo(u0) - mu) * rstd, bf_lo(g.x), bf_hi(g.x));
        o.y = fmaf((bf_hi(u0) - mu) * rstd, bf_lo(g.y), bf_hi(g.y));
        o.z = fmaf((bf_lo(u1) - mu) * rstd, bf_lo(g.z), bf_hi(g.z));
        o.w = fmaf((bf_hi(u1) - mu) * rstd, bf_lo(g.w), bf_hi(g.w));
        __builtin_nontemporal_store(o, (vfloat4*)(orow + c * 4096 + t * 4));
    }
}

extern "C" void kernel_launch(void* const* d_in, const int* in_sizes, int n_in,
                              void* d_out, int out_size, void* d_ws, size_t ws_size,
                              hipStream_t stream) {
    const float* x     = (const float*)d_in[0];   // [1024,1024]
    const float* scale = (const float*)d_in[1];   // [8,1024]
    const float* poly  = (const float*)d_in[2];   // [8,1024,8]
    const float* kern  = (const float*)d_in[3];   // [8,1024,8,8]
    const float* gamma = (const float*)d_in[4];   // [65536]
    const float* beta  = (const float*)d_in[5];   // [65536]
    float* out = (float*)d_out;

    uint4* W3  = (uint4*)d_ws;                          // 1 MiB
    uint4* GB3 = (uint4*)((char*)d_ws + (1u << 20));    // 256 KiB

    fold_weights_kernel<<<256, 256, 0, stream>>>(kern, poly, W3);
    pack_gb_kernel<<<64, 256, 0, stream>>>(gamma, beta, GB3);
    cheb_ln_main<<<1024, 1024, 0, stream>>>(x, scale, W3, GB3, out);
}